// Round 3
// baseline (288.187 us; speedup 1.0000x reference)
//
#include <hip/hip_runtime.h>
#include <stdint.h>
#include <stddef.h>

#define B_ 4
#define S_ 2048
#define D_ 256
#define H_ 4
#define DH_ 64
#define NT 128
#define SC_LOG2E 0.18033688011112042f  // (1/8) * log2(e)

typedef __attribute__((ext_vector_type(8))) short short8;
typedef __attribute__((ext_vector_type(4))) short short4v;
typedef __attribute__((ext_vector_type(4))) float f32x4;
typedef unsigned int uint;

__device__ __forceinline__ short bf16_rne(float f) {
  union { float f; uint32_t u; } c; c.f = f;
  uint32_t u = c.u + 0x7FFFu + ((c.u >> 16) & 1u);
  return (short)(u >> 16);
}

__device__ __forceinline__ f32x4 mfma16(short8 a, short8 b, f32x4 c) {
  return __builtin_amdgcn_mfma_f32_16x16x32_bf16(a, b, c, 0, 0, 0);
}

// ---------------- weight prep: transpose+cast to bf16 ----------------
__global__ void prep_weights(const float* __restrict__ Wq, const float* __restrict__ Wk,
                             const float* __restrict__ Wv,
                             short* __restrict__ WqT, short* __restrict__ WkT,
                             short* __restrict__ WvT) {
  int tid = blockIdx.x * blockDim.x + threadIdx.x;
  if (tid < 65536) {
    int n = tid >> 8, d = tid & 255;
    int hh = n >> 6, e = n & 63;
    WqT[tid] = bf16_rne(Wq[((size_t)hh * D_ + d) * DH_ + e]);
    WkT[tid] = bf16_rne(Wk[((size_t)hh * D_ + d) * DH_ + e]);
  } else if (tid < 65536 + 16384) {
    int t2 = tid - 65536;
    int e = t2 >> 8, d = t2 & 255;
    WvT[t2] = bf16_rne(Wv[(size_t)d * DH_ + e]);
  }
}

// ---------------- mask dtype detect: 1 = int32, 0 = byte/bool ----------------
__global__ void detect_kernel(const unsigned int* __restrict__ m, int* __restrict__ flag) {
  __shared__ int isbool;
  if (threadIdx.x == 0) isbool = 0;
  __syncthreads();
#pragma unroll
  for (int i = 0; i < 4; ++i) {
    unsigned int d = m[threadIdx.x + i * 256];
    if (d & 0xFFFFFFFEu) isbool = 1;
  }
  __syncthreads();
  if (threadIdx.x == 0) *flag = isbool ? 0 : 1;
}

// ---------------- bit-pack mask: [B,S,S] -> [B,S,S/32] dwords ----------------
__global__ __launch_bounds__(256) void pack_mask(const unsigned char* __restrict__ maskB,
                                                 const int* __restrict__ flagp,
                                                 uint* __restrict__ mbits) {
  int tid = blockIdx.x * 256 + threadIdx.x;  // 524288 dwords total
  uint w = 0;
  if (*flagp) {  // int32 mask
    const uint4* p = (const uint4*)((const uint*)maskB + (size_t)tid * 32);
#pragma unroll
    for (int i = 0; i < 8; ++i) {
      uint4 d = p[i];
      w |= (d.x ? 1u : 0u) << (i * 4);
      w |= (d.y ? 1u : 0u) << (i * 4 + 1);
      w |= (d.z ? 1u : 0u) << (i * 4 + 2);
      w |= (d.w ? 1u : 0u) << (i * 4 + 3);
    }
  } else {  // byte mask
    const uint4* p = (const uint4*)(maskB + (size_t)tid * 32);
#pragma unroll
    for (int i = 0; i < 2; ++i) {
      uint4 d = p[i];
      const uint* dw = (const uint*)&d;
#pragma unroll
      for (int j = 0; j < 4; ++j) {
        uint x = dw[j];
        int base = i * 16 + j * 4;
        w |= ((x & 0x000000FFu) ? 1u : 0u) << (base);
        w |= ((x & 0x0000FF00u) ? 1u : 0u) << (base + 1);
        w |= ((x & 0x00FF0000u) ? 1u : 0u) << (base + 2);
        w |= ((x & 0xFF000000u) ? 1u : 0u) << (base + 3);
      }
    }
  }
  mbits[tid] = w;
}

// ---------------- projections ----------------
__global__ __launch_bounds__(256) void proj_kernel(
    const float* __restrict__ X, const short* __restrict__ WT,
    const float* __restrict__ bias, short* __restrict__ outp, int vmode) {
  const int b = blockIdx.z;
  const int s0 = blockIdx.x * 64;
  const int n0 = blockIdx.y * 64;
  const int tid = threadIdx.x;
  const int wave = tid >> 6, lane = tid & 63;
  const int lr = lane & 15, lg = lane >> 4;

  const int arowi = s0 + wave * 16 + lr;
  const float* xr = X + ((size_t)b * S_ + arowi) * D_;

  f32x4 zero4 = {0.f, 0.f, 0.f, 0.f};
  f32x4 acc[4];
#pragma unroll
  for (int ct = 0; ct < 4; ++ct) acc[ct] = zero4;

#pragma unroll
  for (int c = 0; c < 8; ++c) {
    const int k0 = c * 32 + lg * 8;
    f32x4 x0 = *(const f32x4*)(xr + k0);
    f32x4 x1 = *(const f32x4*)(xr + k0 + 4);
    short8 a;
#pragma unroll
    for (int jj = 0; jj < 4; ++jj) { a[jj] = bf16_rne(x0[jj]); a[4 + jj] = bf16_rne(x1[jj]); }
#pragma unroll
    for (int ct = 0; ct < 4; ++ct) {
      short8 bw = *(const short8*)(WT + (size_t)(n0 + ct * 16 + lr) * D_ + k0);
      acc[ct] = mfma16(a, bw, acc[ct]);
    }
  }

  if (vmode == 0) {
#pragma unroll
    for (int ct = 0; ct < 4; ++ct) {
      int n = n0 + ct * 16 + lr;
      float bb = bias[n];
      int hh = n >> 6, e = n & 63;
#pragma unroll
      for (int r = 0; r < 4; ++r) {
        int srow = s0 + wave * 16 + lg * 4 + r;
        outp[(((size_t)b * H_ + hh) * S_ + srow) * DH_ + e] = bf16_rne(acc[ct][r] + bb);
      }
    }
  } else {
#pragma unroll
    for (int ct = 0; ct < 4; ++ct) {
      int n = n0 + ct * 16 + lr;
      float bb = bias[n];
      int s4 = s0 + wave * 16 + lg * 4;
      short4v pk;
#pragma unroll
      for (int r = 0; r < 4; ++r) pk[r] = bf16_rne(acc[ct][r] + bb);
      *(short4v*)(outp + ((size_t)b * DH_ + n) * S_ + s4) = pk;
    }
  }
}

// ---------------- fused masked attention (1 wave / wg, barrier-free) ----------------
// grid (128, H, B), 64 thr. Lane layout (swapped MFMA): q = lr, t = lg*4+r.
// K,V read directly from global (L2-resident). Only P round-trips LDS (wave-local).
__global__ __launch_bounds__(64) void attn_kernel(
    const short* __restrict__ qh, const short* __restrict__ kh,
    const short* __restrict__ vT, const uint* __restrict__ mbits,
    float* __restrict__ attn, float* __restrict__ heads) {
  __shared__ __align__(16) short Pt[16][NT];  // 4 KB, swizzled, per-wave

  const int b = blockIdx.z, h = blockIdx.y;
  const int q0 = blockIdx.x * 16;
  const int lane = threadIdx.x;
  const int lr = lane & 15, lg = lane >> 4;

  const size_t bh = (size_t)b * H_ + h;
  const short* Qb = qh + bh * S_ * DH_;
  const short* Kb = kh + bh * S_ * DH_;
  const short* Vb = vT + (size_t)b * DH_ * S_;

  const int qrow = q0 + lr;
  const uint* mrow = mbits + ((size_t)b * S_ + qrow) * (S_ / 32);
  float* arow = attn + (bh * S_ + qrow) * S_;

  const short8 aq0 = *(const short8*)(Qb + (size_t)qrow * DH_ + lg * 8);
  const short8 aq1 = *(const short8*)(Qb + (size_t)qrow * DH_ + 32 + lg * 8);

  short* pw = &Pt[0][0];

  // -------- pass 1: row sums --------
  float rsum = 0.f;
  for (int t0 = 0; t0 < S_; t0 += NT) {
    uint4 mv = *(const uint4*)(mrow + (t0 >> 5));
#pragma unroll
    for (int j = 0; j < 8; ++j) {
      const short* kr = Kb + (size_t)(t0 + j * 16 + lr) * DH_ + lg * 8;
      short8 bk0 = *(const short8*)(kr);
      short8 bk1 = *(const short8*)(kr + 32);
      f32x4 acc = {0.f, 0.f, 0.f, 0.f};
      acc = mfma16(bk0, aq0, acc);
      acc = mfma16(bk1, aq1, acc);
      uint mw = ((const uint*)&mv)[j >> 1];
#pragma unroll
      for (int r = 0; r < 4; ++r) {
        int sh = (j & 1) * 16 + lg * 4 + r;
        float p = ((mw >> sh) & 1u) ? 0.f : __builtin_exp2f(acc[r] * SC_LOG2E);
        rsum += p;
      }
    }
  }
  rsum += __shfl_xor(rsum, 16);
  rsum += __shfl_xor(rsum, 32);
  const float rinv = 1.0f / rsum;

  // -------- pass 2: recompute, write attn (float4), PV --------
  f32x4 o[4];
#pragma unroll
  for (int ct = 0; ct < 4; ++ct) o[ct] = (f32x4){0.f, 0.f, 0.f, 0.f};

  for (int t0 = 0; t0 < S_; t0 += NT) {
    uint4 mv = *(const uint4*)(mrow + (t0 >> 5));
#pragma unroll
    for (int j = 0; j < 8; ++j) {
      const short* kr = Kb + (size_t)(t0 + j * 16 + lr) * DH_ + lg * 8;
      short8 bk0 = *(const short8*)(kr);
      short8 bk1 = *(const short8*)(kr + 32);
      f32x4 acc = {0.f, 0.f, 0.f, 0.f};
      acc = mfma16(bk0, aq0, acc);
      acc = mfma16(bk1, aq1, acc);
      uint mw = ((const uint*)&mv)[j >> 1];
      f32x4 pst;
      short4v pk;
#pragma unroll
      for (int r = 0; r < 4; ++r) {
        int sh = (j & 1) * 16 + lg * 4 + r;
        float p = ((mw >> sh) & 1u) ? 0.f : __builtin_exp2f(acc[r] * SC_LOG2E) * rinv;
        pst[r] = p;
        pk[r] = bf16_rne(p);
      }
      *(f32x4*)(arow + t0 + j * 16 + lg * 4) = pst;
      int slot = j * 2 + (lg >> 1);
      *(short4v*)(pw + lr * 128 + ((slot ^ lr) * 8) + (lg & 1) * 4) = pk;
    }
    // PV: o[e][q] += V^T[e][t] * P[q][t]
#pragma unroll
    for (int ct = 0; ct < 4; ++ct) {
#pragma unroll
      for (int kc = 0; kc < 4; ++kc) {
        short8 apf = *(const short8*)(pw + lr * 128 + (((kc * 4 + lg) ^ lr) * 8));
        short8 bvf = *(const short8*)(Vb + (size_t)(ct * 16 + lr) * S_ + t0 + kc * 32 + lg * 8);
        o[ct] = mfma16(bvf, apf, o[ct]);
      }
    }
  }

#pragma unroll
  for (int ct = 0; ct < 4; ++ct)
    *(f32x4*)(heads + (bh * S_ + qrow) * DH_ + ct * 16 + lg * 4) = o[ct];
}

// ---------------- mean over heads + final projection ----------------
__global__ __launch_bounds__(256) void final_kernel(
    const float* __restrict__ heads, const float* __restrict__ Wf,
    float* __restrict__ outp) {
  __shared__ float mean[16][DH_];
  const int row0 = blockIdx.x * 16;
  const int tid = threadIdx.x;
#pragma unroll
  for (int i = 0; i < 4; ++i) {
    int idx = tid + i * 256;
    int r = idx >> 6, e = idx & 63;
    int gs = row0 + r;
    int bb = gs >> 11, ss = gs & (S_ - 1);
    float acc = 0.f;
#pragma unroll
    for (int hh = 0; hh < H_; ++hh)
      acc += heads[(((size_t)bb * H_ + hh) * S_ + ss) * DH_ + e];
    mean[r][e] = acc * 0.25f;
  }
  __syncthreads();
  float acc[16];
#pragma unroll
  for (int r = 0; r < 16; ++r) acc[r] = 0.f;
  for (int e = 0; e < DH_; ++e) {
    float wf = Wf[(size_t)e * D_ + tid];
#pragma unroll
    for (int r = 0; r < 16; ++r) acc[r] += mean[r][e] * wf;
  }
#pragma unroll
  for (int r = 0; r < 16; ++r)
    outp[(size_t)(row0 + r) * D_ + tid] = acc[r];
}

extern "C" void kernel_launch(void* const* d_in, const int* in_sizes, int n_in,
                              void* d_out, int out_size, void* d_ws, size_t ws_size,
                              hipStream_t stream) {
  (void)in_sizes; (void)n_in; (void)out_size; (void)ws_size;
  const float* q  = (const float*)d_in[0];
  const float* k  = (const float*)d_in[1];
  const float* v  = (const float*)d_in[2];
  const unsigned char* mask = (const unsigned char*)d_in[3];
  const float* Wq = (const float*)d_in[4];
  const float* bq = (const float*)d_in[5];
  const float* Wk = (const float*)d_in[6];
  const float* bk = (const float*)d_in[7];
  const float* Wv = (const float*)d_in[8];
  const float* bv = (const float*)d_in[9];
  const float* Wf = (const float*)d_in[10];

  float* out  = (float*)d_out;
  float* attn = out + (size_t)B_ * S_ * D_;

  char* ws = (char*)d_ws;
  short* qh    = (short*)(ws);
  short* kh    = (short*)(ws + 4194304);
  short* vT    = (short*)(ws + 8388608);
  short* WqT   = (short*)(ws + 9437184);
  short* WkT   = (short*)(ws + 9568256);
  short* WvT   = (short*)(ws + 9699328);
  float* heads = (float*)(ws + 9732096);
  int*   flag  = (int*)(ws + 18120704);
  uint*  mbits = (uint*)(ws + 18120768);  // 2 MB bit-packed mask

  detect_kernel<<<1, 256, 0, stream>>>((const unsigned int*)mask, flag);
  pack_mask<<<2048, 256, 0, stream>>>(mask, flag, mbits);
  prep_weights<<<320, 256, 0, stream>>>(Wq, Wk, Wv, WqT, WkT, WvT);
  proj_kernel<<<dim3(32, 4, B_), 256, 0, stream>>>(q, WqT, bq, qh, 0);
  proj_kernel<<<dim3(32, 4, B_), 256, 0, stream>>>(k, WkT, bk, kh, 0);
  proj_kernel<<<dim3(32, 1, B_), 256, 0, stream>>>(v, WvT, bv, vT, 1);
  attn_kernel<<<dim3(128, H_, B_), 64, 0, stream>>>(qh, kh, vT, mbits, attn, heads);
  final_kernel<<<512, 256, 0, stream>>>(heads, Wf, out);
}